// Round 1
// 258.810 us; speedup vs baseline: 1.1850x; 1.1850x over previous
//
#include <hip/hip_runtime.h>
#include <cstdint>
#include <cstddef>

// ---------------------------------------------------------------------------
// GCN 2-layer + 2 heads. N=100000 (<2^17), E=1.6M.
//   CSR:    slack-capacity segmented buckets (pass1/pass2), line-padded gcur
//   cast:   xh = bf16(dinv ⊙ x)    (pre-scaled: pull1 needs no dinv gather)
//   pull1:  aggh = bf16(dinv ⊙ (Â-gather))   (pull2-style, bf16 out)
//   gemm12: g2h = bf16(dinv ⊙ relu(aggh@W1+b1)@W2)  -- fused bf16 MFMA,
//           h1 lives only in LDS (kills the 102MB h1 HBM round-trip),
//           16x16x32 MFMA, XOR-swizzled LDS (T2), 80KB -> 2 blocks/CU
//   pull2:  bf16 gather + relu + both heads fused
// ---------------------------------------------------------------------------

#define MAXC 512   // max coarse buckets (N <= 131072)
#define CAP  6144  // slots per bucket; mean 4093, sigma 64 -> no overflow
#define SEG  3456  // max edges per pass1 block (LDS-staged)
#define GPAD 16    // gcur stride in ints (one counter per 64B line)

typedef __attribute__((ext_vector_type(8))) short bf16x8;
typedef __attribute__((ext_vector_type(4))) float f32x4;

__device__ __forceinline__ float blo(unsigned int u) {
  return __uint_as_float(u << 16);
}
__device__ __forceinline__ float bhi(unsigned int u) {
  return __uint_as_float(u & 0xffff0000u);
}
__device__ __forceinline__ unsigned short f2b(float f) {  // RNE pack
  unsigned int u = __float_as_uint(f);
  unsigned int r = u + 0x7fffu + ((u >> 16) & 1u);
  return (unsigned short)(r >> 16);
}

// --- cast x[N*64] f32 -> xh bf16, pre-scaled by dinv[node] (runs AFTER pass2)
__global__ __launch_bounds__(256) void k_cast(const float* __restrict__ x,
                                              const float* __restrict__ dinv,
                                              unsigned int* __restrict__ xh,
                                              int n16) {  // n16 = N*16 float4s
  int i = blockIdx.x * 256 + threadIdx.x;
  if (i >= n16) return;
  float di = dinv[i >> 4];
  float4 v = reinterpret_cast<const float4*>(x)[i];
  uint2 o;
  o.x = (unsigned int)f2b(v.x * di) | ((unsigned int)f2b(v.y * di) << 16);
  o.y = (unsigned int)f2b(v.z * di) | ((unsigned int)f2b(v.w * di) << 16);
  reinterpret_cast<uint2*>(xh)[i] = o;
}

// --- bucket cursors: segmented regions of CAP slots, line-padded ---
__global__ void k_binit(int* __restrict__ gcur, int nc) {
  int b = blockIdx.x * 256 + threadIdx.x;
  if (b < nc) gcur[b * GPAD] = b * CAP;
}

// --- pass1: block-local counting sort by bucket, coalesced write-out ---
__global__ __launch_bounds__(256) void k_pass1(const int* __restrict__ src,
                                               const int* __restrict__ dst,
                                               int* __restrict__ gcur,
                                               int* __restrict__ P,
                                               int E, int nc, int seg) {
  __shared__ int hist[MAXC];
  __shared__ int lofs[MAXC];
  __shared__ int base[MAXC];
  __shared__ int sbuf[SEG];
  __shared__ unsigned short dbuf[SEG];
  __shared__ int ssc[256];
  int tid = threadIdx.x;
  int start = blockIdx.x * seg;
  int end = min(E, start + seg);
  int cnt = end - start;
  if (cnt <= 0) return;
  for (int i = tid; i < MAXC; i += 256) hist[i] = 0;
  __syncthreads();
  for (int i = start + tid; i < end; i += 256)
    atomicAdd(&hist[dst[i] >> 8], 1);
  __syncthreads();
  int p0 = hist[2 * tid], p1 = hist[2 * tid + 1];
  int ps = p0 + p1;
  ssc[tid] = ps;
  __syncthreads();
  for (int off = 1; off < 256; off <<= 1) {
    int t = (tid >= off) ? ssc[tid - off] : 0;
    __syncthreads();
    ssc[tid] += t;
    __syncthreads();
  }
  int pe = ssc[tid] - ps;
  lofs[2 * tid] = pe;
  lofs[2 * tid + 1] = pe + p0;
  __syncthreads();
  for (int b = tid; b < nc; b += 256) {
    int h = hist[b];
    base[b] = (h ? atomicAdd(&gcur[b * GPAD], h) : 0) - lofs[b];
  }
  __syncthreads();
  for (int i = tid; i < MAXC; i += 256) hist[i] = lofs[i];
  __syncthreads();
  for (int i = start + tid; i < end; i += 256) {
    int d = dst[i];
    int b = d >> 8;
    int r = atomicAdd(&hist[b], 1);
    sbuf[r] = src[i] | ((d & 255) << 17);
    dbuf[r] = (unsigned short)b;
  }
  __syncthreads();
  for (int j = tid; j < cnt; j += 256) {
    P[base[dbuf[j]] + j] = sbuf[j];
  }
}

// --- per-bucket: LDS count+scan -> rs/c/dinv, then place col ---
__global__ __launch_bounds__(256) void k_pass2(const int* __restrict__ P,
                                               const int* __restrict__ gcur,
                                               int* __restrict__ rs,
                                               int* __restrict__ c,
                                               float* __restrict__ dinv,
                                               int* __restrict__ col, int N) {
  __shared__ int sh[256];
  __shared__ int lcur[256];
  int tid = threadIdx.x;
  int node0 = blockIdx.x << 8;
  int begin = blockIdx.x * CAP;
  int end = gcur[blockIdx.x * GPAD];
  sh[tid] = 0;
  __syncthreads();
  for (int i = begin + tid; i < end; i += 256)
    atomicAdd(&sh[P[i] >> 17], 1);
  __syncthreads();
  int s = sh[tid];
  for (int off = 1; off < 256; off <<= 1) {
    int t = (tid >= off) ? sh[tid - off] : 0;
    __syncthreads();
    sh[tid] += t;
    __syncthreads();
  }
  int excl = sh[tid] - s;
  int node = node0 + tid;
  if (node < N) {
    rs[node] = begin + excl;
    c[node] = s;
    dinv[node] = rsqrtf((float)(s + 1));
  }
  lcur[tid] = begin + excl;
  __syncthreads();
  for (int i = begin + tid; i < end; i += 256) {
    int p = P[i];
    int pos = atomicAdd(&lcur[p >> 17], 1);
    col[pos] = p & 0x1FFFF;
  }
}

// --- pull1: bf16 gather (xh pre-scaled by dinv), bf16 out for MFMA gemm ---
__global__ __launch_bounds__(256) void k_pull1(const unsigned int* __restrict__ xh,
                                               const float* __restrict__ x,
                                               const int* __restrict__ rs,
                                               const int* __restrict__ cnt,
                                               const int* __restrict__ col,
                                               const float* __restrict__ dinv,
                                               unsigned int* __restrict__ aggh,
                                               int n) {
  int node = (blockIdx.x * 256 + threadIdx.x) >> 6;
  int lane = threadIdx.x & 63;
  if (node >= n) return;
  int q = lane & 15;
  int grp = lane >> 4;
  int start = rs[node], m = cnt[node];
  const uint2* xr = reinterpret_cast<const uint2*>(xh);
  float4 acc = {0.f, 0.f, 0.f, 0.f};
  for (int base0 = 0; base0 < m; base0 += 64) {
    int lim = min(64, m - base0);
    int idx = (lane < lim) ? col[start + base0 + lane] : 0;
    int nt = lim >> 2;
    int t = 0;
    for (; t + 4 <= nt; t += 4) {
      int e0 = t * 4 + grp, e1 = e0 + 4, e2 = e0 + 8, e3 = e0 + 12;
      int s0 = __shfl(idx, e0), s1 = __shfl(idx, e1);
      int s2 = __shfl(idx, e2), s3 = __shfl(idx, e3);
      uint2 v0 = xr[(size_t)s0 * 16 + q];
      uint2 v1 = xr[(size_t)s1 * 16 + q];
      uint2 v2 = xr[(size_t)s2 * 16 + q];
      uint2 v3 = xr[(size_t)s3 * 16 + q];
      acc.x += (blo(v0.x) + blo(v1.x)) + (blo(v2.x) + blo(v3.x));
      acc.y += (bhi(v0.x) + bhi(v1.x)) + (bhi(v2.x) + bhi(v3.x));
      acc.z += (blo(v0.y) + blo(v1.y)) + (blo(v2.y) + blo(v3.y));
      acc.w += (bhi(v0.y) + bhi(v1.y)) + (bhi(v2.y) + bhi(v3.y));
    }
    for (; t + 2 <= nt; t += 2) {
      int e0 = t * 4 + grp, e1 = e0 + 4;
      int s0 = __shfl(idx, e0), s1 = __shfl(idx, e1);
      uint2 v0 = xr[(size_t)s0 * 16 + q];
      uint2 v1 = xr[(size_t)s1 * 16 + q];
      acc.x += blo(v0.x) + blo(v1.x); acc.y += bhi(v0.x) + bhi(v1.x);
      acc.z += blo(v0.y) + blo(v1.y); acc.w += bhi(v0.y) + bhi(v1.y);
    }
    if (t < nt) {
      int e0 = t * 4 + grp;
      int s0 = __shfl(idx, e0);
      uint2 v0 = xr[(size_t)s0 * 16 + q];
      acc.x += blo(v0.x); acc.y += bhi(v0.x);
      acc.z += blo(v0.y); acc.w += bhi(v0.y);
    }
    for (int j = nt * 4; j < lim; ++j) {
      int s0 = __shfl(idx, j);
      if (grp == (j & 3)) {
        uint2 v0 = xr[(size_t)s0 * 16 + q];
        acc.x += blo(v0.x); acc.y += bhi(v0.x);
        acc.z += blo(v0.y); acc.w += bhi(v0.y);
      }
    }
  }
  acc.x += __shfl_xor(acc.x, 16); acc.y += __shfl_xor(acc.y, 16);
  acc.z += __shfl_xor(acc.z, 16); acc.w += __shfl_xor(acc.w, 16);
  acc.x += __shfl_xor(acc.x, 32); acc.y += __shfl_xor(acc.y, 32);
  acc.z += __shfl_xor(acc.z, 32); acc.w += __shfl_xor(acc.w, 32);
  float di = dinv[node];
  float4 xs = *reinterpret_cast<const float4*>(x + (size_t)node * 64 + q * 4);
  acc.x = fmaf(di, xs.x, acc.x); acc.y = fmaf(di, xs.y, acc.y);
  acc.z = fmaf(di, xs.z, acc.z); acc.w = fmaf(di, xs.w, acc.w);
  if (lane < 16) {
    uint2 o;
    o.x = (unsigned int)f2b(acc.x * di) | ((unsigned int)f2b(acc.y * di) << 16);
    o.y = (unsigned int)f2b(acc.z * di) | ((unsigned int)f2b(acc.w * di) << 16);
    reinterpret_cast<uint2*>(aggh)[(size_t)node * 16 + q] = o;
  }
}

// --- fused gemm12: g2h = bf16(dinv ⊙ relu(aggh@W1+b1)@W2), bf16 MFMA ---
// LDS (80KB, 2 blocks/CU): aggh[128][64]bf16 @0, W1t[128][64]bf16 @16K,
// W2t[64][128]bf16 @32K, h1[128][128]bf16 / C2[128][64]f32 (reused) @48K.
// All tiles XOR-swizzled: frag reads are 16-lanes-same-column at 128/256B
// row stride -> 16-way bank conflict unswizzled (T2).
#define OFF_W1T 16384
#define OFF_W2T 32768
#define OFF_H1  49152
__global__ __launch_bounds__(256) void k_gemm12(
    const unsigned int* __restrict__ aggh,
    const float* __restrict__ W1, const float* __restrict__ b1,
    const float* __restrict__ W2, const float* __restrict__ dinv,
    unsigned int* __restrict__ g2h, int n) {
  __shared__ __align__(16) char smem[81920];
  int tid = threadIdx.x;
  int lane = tid & 63;
  int wid = tid >> 6;
  int lr = lane & 15, lg = lane >> 4;
  int wr = wid >> 1, wc = wid & 1;
  // stage W1t bf16 [ncol=128][k=64]: B-frag wants 8 consecutive k at row=ncol
  {
    int nrow = tid >> 1, h = tid & 1;
    unsigned int pk[16];
#pragma unroll
    for (int q = 0; q < 16; ++q) {
      unsigned short a = f2b(W1[(size_t)(h * 32 + 2 * q) * 128 + nrow]);
      unsigned short bq = f2b(W1[(size_t)(h * 32 + 2 * q + 1) * 128 + nrow]);
      pk[q] = (unsigned int)a | ((unsigned int)bq << 16);
    }
#pragma unroll
    for (int cc = 0; cc < 4; ++cc) {
      uint4 v = make_uint4(pk[cc * 4], pk[cc * 4 + 1], pk[cc * 4 + 2], pk[cc * 4 + 3]);
      int byte = nrow * 128 + ((h * 64 + cc * 16) ^ ((nrow & 7) << 4));
      *reinterpret_cast<uint4*>(smem + OFF_W1T + byte) = v;
    }
  }
  // stage W2t bf16 [ncol=64][k=128]
  {
    int nrow = tid >> 2, qt = tid & 3;
    unsigned int pk[16];
#pragma unroll
    for (int q = 0; q < 16; ++q) {
      unsigned short a = f2b(W2[(size_t)(qt * 32 + 2 * q) * 64 + nrow]);
      unsigned short bq = f2b(W2[(size_t)(qt * 32 + 2 * q + 1) * 64 + nrow]);
      pk[q] = (unsigned int)a | ((unsigned int)bq << 16);
    }
#pragma unroll
    for (int cc = 0; cc < 4; ++cc) {
      uint4 v = make_uint4(pk[cc * 4], pk[cc * 4 + 1], pk[cc * 4 + 2], pk[cc * 4 + 3]);
      int byte = nrow * 256 + ((qt * 64 + cc * 16) ^ ((nrow & 7) << 4));
      *reinterpret_cast<uint4*>(smem + OFF_W2T + byte) = v;
    }
  }
  float bias[4];
#pragma unroll
  for (int ni = 0; ni < 4; ++ni) bias[ni] = b1[wc * 64 + ni * 16 + lr];

  int ntiles = (n + 127) >> 7;
  for (int tile = blockIdx.x; tile < ntiles; tile += gridDim.x) {
    int row0 = tile << 7;
    __syncthreads();  // prev epilogue done reading OFF_H1 / first: W staged
    // stage aggh tile [r=128][k=64] bf16, swizzled
#pragma unroll
    for (int j = 0; j < 4; ++j) {
      int idx = tid + 256 * j;
      int r = idx >> 3, u = idx & 7;
      uint4 v = make_uint4(0u, 0u, 0u, 0u);
      int row = row0 + r;
      if (row < n) v = reinterpret_cast<const uint4*>(aggh)[(size_t)row * 8 + u];
      int byte = r * 128 + ((u * 16) ^ ((r & 7) << 4));
      *reinterpret_cast<uint4*>(smem + byte) = v;
    }
    __syncthreads();
    // phase 1: C1[128][128] = aggh @ W1 ; wave(wr,wc): rows wr*64+, cols wc*64+
    f32x4 acc1[4][4];
#pragma unroll
    for (int mi = 0; mi < 4; ++mi)
#pragma unroll
      for (int ni = 0; ni < 4; ++ni) {
        f32x4 z = {0.f, 0.f, 0.f, 0.f};
        acc1[mi][ni] = z;
      }
#pragma unroll
    for (int kk = 0; kk < 2; ++kk) {
      int kb = kk * 64 + lg * 16;  // k*2 bytes, k = kk*32 + lg*8
      bf16x8 af[4], bfq[4];
#pragma unroll
      for (int mi = 0; mi < 4; ++mi) {
        int r = wr * 64 + mi * 16 + lr;
        af[mi] = *reinterpret_cast<const bf16x8*>(smem + r * 128 + (kb ^ ((r & 7) << 4)));
      }
#pragma unroll
      for (int ni = 0; ni < 4; ++ni) {
        int nr = wc * 64 + ni * 16 + lr;
        bfq[ni] = *reinterpret_cast<const bf16x8*>(smem + OFF_W1T + nr * 128 + (kb ^ ((nr & 7) << 4)));
      }
#pragma unroll
      for (int mi = 0; mi < 4; ++mi)
#pragma unroll
        for (int ni = 0; ni < 4; ++ni)
          acc1[mi][ni] = __builtin_amdgcn_mfma_f32_16x16x32_bf16(
              af[mi], bfq[ni], acc1[mi][ni], 0, 0, 0);
    }
    // h1 = relu(C1+b1) -> bf16 LDS [m=128][k=128] swizzled (scalar b16 writes;
    // C-frag is col-fixed/row-varying so no wider pack exists)
#pragma unroll
    for (int mi = 0; mi < 4; ++mi) {
      int m0 = wr * 64 + mi * 16 + lg * 4;
#pragma unroll
      for (int ni = 0; ni < 4; ++ni) {
        int kcol = wc * 64 + ni * 16 + lr;
#pragma unroll
        for (int rj = 0; rj < 4; ++rj) {
          float v = fmaxf(acc1[mi][ni][rj] + bias[ni], 0.f);
          int mm = m0 + rj;
          int byte = mm * 256 + ((kcol * 2) ^ ((mm & 15) << 4));
          *reinterpret_cast<unsigned short*>(smem + OFF_H1 + byte) = f2b(v);
        }
      }
    }
    __syncthreads();
    // phase 2: C2[128][64] = h1 @ W2 ; wave(wr,wc): rows wr*64+, cols wc*32+
    f32x4 acc2[4][2];
#pragma unroll
    for (int mi = 0; mi < 4; ++mi)
#pragma unroll
      for (int ni = 0; ni < 2; ++ni) {
        f32x4 z = {0.f, 0.f, 0.f, 0.f};
        acc2[mi][ni] = z;
      }
#pragma unroll
    for (int kk = 0; kk < 4; ++kk) {
      int kb = kk * 64 + lg * 16;
      bf16x8 af[4], bfq[2];
#pragma unroll
      for (int mi = 0; mi < 4; ++mi) {
        int m = wr * 64 + mi * 16 + lr;
        af[mi] = *reinterpret_cast<const bf16x8*>(smem + OFF_H1 + m * 256 + (kb ^ ((m & 15) << 4)));
      }
#pragma unroll
      for (int ni = 0; ni < 2; ++ni) {
        int nr = wc * 32 + ni * 16 + lr;
        bfq[ni] = *reinterpret_cast<const bf16x8*>(smem + OFF_W2T + nr * 256 + (kb ^ ((nr & 7) << 4)));
      }
#pragma unroll
      for (int mi = 0; mi < 4; ++mi)
#pragma unroll
        for (int ni = 0; ni < 2; ++ni)
          acc2[mi][ni] = __builtin_amdgcn_mfma_f32_16x16x32_bf16(
              af[mi], bfq[ni], acc2[mi][ni], 0, 0, 0);
    }
    __syncthreads();  // done reading h1; reuse OFF_H1 as C2 f32 [m=128][n=64]
#pragma unroll
    for (int mi = 0; mi < 4; ++mi) {
      int m0 = wr * 64 + mi * 16 + lg * 4;
#pragma unroll
      for (int ni = 0; ni < 2; ++ni) {
        int nn = wc * 32 + ni * 16 + lr;
#pragma unroll
        for (int rj = 0; rj < 4; ++rj) {
          int mm = m0 + rj;
          int byte = mm * 256 + ((nn * 4) ^ ((mm & 15) << 4));
          *reinterpret_cast<float*>(smem + OFF_H1 + byte) = acc2[mi][ni][rj];
        }
      }
    }
    __syncthreads();
    // epilogue: scale rows by dinv, pack bf16, coalesced store
#pragma unroll
    for (int j = 0; j < 8; ++j) {
      int idx = tid + 256 * j;
      int r = idx >> 4, c4 = idx & 15;
      int row = row0 + r;
      if (row < n) {
        float4 v = *reinterpret_cast<const float4*>(
            smem + OFF_H1 + r * 256 + ((c4 * 16) ^ ((r & 15) << 4)));
        float di = dinv[row];
        uint2 o;
        o.x = (unsigned int)f2b(v.x * di) | ((unsigned int)f2b(v.y * di) << 16);
        o.y = (unsigned int)f2b(v.z * di) | ((unsigned int)f2b(v.w * di) << 16);
        reinterpret_cast<uint2*>(g2h)[(size_t)row * 16 + c4] = o;
      }
    }
  }
}

// --- pull2: bf16 gather (4-deep) + relu + both heads fused ---
__global__ __launch_bounds__(256) void k_pull2(const unsigned int* __restrict__ g2h,
                                               const int* __restrict__ rs,
                                               const int* __restrict__ cnt,
                                               const int* __restrict__ col,
                                               const float* __restrict__ dinv,
                                               const float* __restrict__ b,
                                               const float* __restrict__ Wd,
                                               const float* __restrict__ Wp,
                                               const float* __restrict__ bd,
                                               const float* __restrict__ bp,
                                               float* __restrict__ out, int n) {
  int node = (blockIdx.x * 256 + threadIdx.x) >> 6;
  int lane = threadIdx.x & 63;
  if (node >= n) return;
  int q = lane & 15;
  int grp = lane >> 4;
  int start = rs[node], m = cnt[node];
  const uint2* gr = reinterpret_cast<const uint2*>(g2h);
  float4 acc = {0.f, 0.f, 0.f, 0.f};
  for (int base0 = 0; base0 < m; base0 += 64) {
    int lim = min(64, m - base0);
    int idx = (lane < lim) ? col[start + base0 + lane] : 0;
    int nt = lim >> 2;
    int t = 0;
    for (; t + 4 <= nt; t += 4) {
      int e0 = t * 4 + grp, e1 = e0 + 4, e2 = e0 + 8, e3 = e0 + 12;
      int s0 = __shfl(idx, e0), s1 = __shfl(idx, e1);
      int s2 = __shfl(idx, e2), s3 = __shfl(idx, e3);
      uint2 v0 = gr[(size_t)s0 * 16 + q];
      uint2 v1 = gr[(size_t)s1 * 16 + q];
      uint2 v2 = gr[(size_t)s2 * 16 + q];
      uint2 v3 = gr[(size_t)s3 * 16 + q];
      acc.x += (blo(v0.x) + blo(v1.x)) + (blo(v2.x) + blo(v3.x));
      acc.y += (bhi(v0.x) + bhi(v1.x)) + (bhi(v2.x) + bhi(v3.x));
      acc.z += (blo(v0.y) + blo(v1.y)) + (blo(v2.y) + blo(v3.y));
      acc.w += (bhi(v0.y) + bhi(v1.y)) + (bhi(v2.y) + bhi(v3.y));
    }
    for (; t + 2 <= nt; t += 2) {
      int e0 = t * 4 + grp, e1 = e0 + 4;
      int s0 = __shfl(idx, e0), s1 = __shfl(idx, e1);
      uint2 v0 = gr[(size_t)s0 * 16 + q];
      uint2 v1 = gr[(size_t)s1 * 16 + q];
      acc.x += blo(v0.x) + blo(v1.x); acc.y += bhi(v0.x) + bhi(v1.x);
      acc.z += blo(v0.y) + blo(v1.y); acc.w += bhi(v0.y) + bhi(v1.y);
    }
    if (t < nt) {
      int e0 = t * 4 + grp;
      int s0 = __shfl(idx, e0);
      uint2 v0 = gr[(size_t)s0 * 16 + q];
      acc.x += blo(v0.x); acc.y += bhi(v0.x);
      acc.z += blo(v0.y); acc.w += bhi(v0.y);
    }
    for (int j = nt * 4; j < lim; ++j) {
      int s0 = __shfl(idx, j);
      if (grp == (j & 3)) {
        uint2 v0 = gr[(size_t)s0 * 16 + q];
        acc.x += blo(v0.x); acc.y += bhi(v0.x);
        acc.z += blo(v0.y); acc.w += bhi(v0.y);
      }
    }
  }
  acc.x += __shfl_xor(acc.x, 16); acc.y += __shfl_xor(acc.y, 16);
  acc.z += __shfl_xor(acc.z, 16); acc.w += __shfl_xor(acc.w, 16);
  acc.x += __shfl_xor(acc.x, 32); acc.y += __shfl_xor(acc.y, 32);
  acc.z += __shfl_xor(acc.z, 32); acc.w += __shfl_xor(acc.w, 32);
  {
    uint2 sv = gr[(size_t)node * 16 + q];
    acc.x += blo(sv.x); acc.y += bhi(sv.x);
    acc.z += blo(sv.y); acc.w += bhi(sv.y);
  }
  float di = dinv[node];
  float4 b4 = *reinterpret_cast<const float4*>(b + q * 4);
  float4 wd4 = *reinterpret_cast<const float4*>(Wd + q * 4);
  float4 wp4 = *reinterpret_cast<const float4*>(Wp + q * 4);
  float vx = fmaxf(fmaf(acc.x, di, b4.x), 0.f);
  float vy = fmaxf(fmaf(acc.y, di, b4.y), 0.f);
  float vz = fmaxf(fmaf(acc.z, di, b4.z), 0.f);
  float vw = fmaxf(fmaf(acc.w, di, b4.w), 0.f);
  float dsum = vx * wd4.x + vy * wd4.y + vz * wd4.z + vw * wd4.w;
  float psum = vx * wp4.x + vy * wp4.y + vz * wp4.z + vw * wp4.w;
#pragma unroll
  for (int off = 1; off < 16; off <<= 1) {
    dsum += __shfl_xor(dsum, off);
    psum += __shfl_xor(psum, off);
  }
  if (lane == 0) {
    out[node] = dsum + bd[0];
    out[n + node] = psum + bp[0];
  }
}

extern "C" void kernel_launch(void* const* d_in, const int* in_sizes, int n_in,
                              void* d_out, int out_size, void* d_ws, size_t ws_size,
                              hipStream_t stream) {
  const float* x  = (const float*)d_in[0];
  const int*   ei = (const int*)d_in[1];
  const float* W1 = (const float*)d_in[2];
  const float* b1 = (const float*)d_in[3];
  const float* W2 = (const float*)d_in[4];
  const float* b2 = (const float*)d_in[5];
  const float* Wd = (const float*)d_in[6];
  const float* bd = (const float*)d_in[7];
  const float* Wp = (const float*)d_in[8];
  const float* bp = (const float*)d_in[9];
  float* out = (float*)d_out;

  const int N = in_sizes[0] / 64;
  const int E = in_sizes[1] / 2;
  const int* src = ei;
  const int* dst = ei + E;
  const int nc = (N + 255) >> 8;

  char* ws = (char*)d_ws;
  size_t off = 0;
  auto alloc = [&](size_t bytes) -> void* {
    size_t a = (off + 255) & ~(size_t)255;
    off = a + bytes;
    return (void*)(ws + a);
  };

  int*   gcur = (int*)alloc((size_t)MAXC * GPAD * 4);
  int*   rs   = (int*)alloc((size_t)N * 4);
  int*   c    = (int*)alloc((size_t)N * 4);
  float* dinv = (float*)alloc((size_t)N * 4);
  int*   P    = (int*)alloc((size_t)nc * CAP * 4);
  int*   col  = (int*)alloc((size_t)nc * CAP * 4);
  unsigned int* xh   = (unsigned int*)alloc((size_t)N * 64 * 2);
  unsigned int* aggh = (unsigned int*)alloc((size_t)N * 64 * 2);
  unsigned int* g2h  = (unsigned int*)alloc((size_t)N * 64 * 2);
  (void)ws_size; (void)n_in; (void)out_size;

  k_binit<<<(nc + 255) / 256, 256, 0, stream>>>(gcur, nc);

  int nb1 = 512;
  int seg = (E + nb1 - 1) / nb1;
  while (seg > SEG) { nb1 *= 2; seg = (E + nb1 - 1) / nb1; }
  k_pass1<<<nb1, 256, 0, stream>>>(src, dst, gcur, P, E, nc, seg);
  k_pass2<<<nc, 256, 0, stream>>>(P, gcur, rs, c, dinv, col, N);

  k_cast<<<(N * 16 + 255) / 256, 256, 0, stream>>>(x, dinv, xh, N * 16);
  k_pull1<<<(N + 3) / 4, 256, 0, stream>>>(xh, x, rs, c, col, dinv, aggh, N);
  k_gemm12<<<512, 256, 0, stream>>>(aggh, W1, b1, W2, dinv, g2h, N);
  k_pull2<<<(N + 3) / 4, 256, 0, stream>>>(g2h, rs, c, col, dinv, b2, Wd, Wp, bd, bp, out, N);
}

// Round 2
// 222.176 us; speedup vs baseline: 1.3803x; 1.1649x over previous
//
#include <hip/hip_runtime.h>
#include <cstdint>
#include <cstddef>

// ---------------------------------------------------------------------------
// GCN 2-layer + 2 heads. N=100000 (<2^17), E=1.6M.
//   CSR:    slack-capacity segmented buckets (pass1/pass2), line-padded gcur
//   cast:   xh = bf16(dinv ⊙ x)    (pre-scaled: pulls need no dinv gather)
//   pull1:  aggh = bf16(dinv ⊙ (Â-gather))   16-lane-per-node, bcast col,
//           8-deep unrolled gather (R1: kills per-node shuffle chains; 4x MLP)
//   gemm12: g2h = bf16(dinv ⊙ relu(aggh@W1+b1)@W2)  -- fused bf16 MFMA,
//           h1 lives only in LDS, XOR-swizzled tiles, 80KB -> 2 blocks/CU
//   pull2:  same gather structure + relu + both heads (16-lane reduce only)
// ---------------------------------------------------------------------------

#define MAXC 512   // max coarse buckets (N <= 131072)
#define CAP  6144  // slots per bucket; mean 4093, sigma 64 -> no overflow
#define SEG  3456  // max edges per pass1 block (LDS-staged)
#define GPAD 16    // gcur stride in ints (one counter per 64B line)

typedef __attribute__((ext_vector_type(8))) short bf16x8;
typedef __attribute__((ext_vector_type(4))) float f32x4;

__device__ __forceinline__ float blo(unsigned int u) {
  return __uint_as_float(u << 16);
}
__device__ __forceinline__ float bhi(unsigned int u) {
  return __uint_as_float(u & 0xffff0000u);
}
__device__ __forceinline__ unsigned short f2b(float f) {  // RNE pack
  unsigned int u = __float_as_uint(f);
  unsigned int r = u + 0x7fffu + ((u >> 16) & 1u);
  return (unsigned short)(r >> 16);
}

// --- cast x[N*64] f32 -> xh bf16, pre-scaled by dinv[node] (runs AFTER pass2)
__global__ __launch_bounds__(256) void k_cast(const float* __restrict__ x,
                                              const float* __restrict__ dinv,
                                              unsigned int* __restrict__ xh,
                                              int n16) {  // n16 = N*16 float4s
  int i = blockIdx.x * 256 + threadIdx.x;
  if (i >= n16) return;
  float di = dinv[i >> 4];
  float4 v = reinterpret_cast<const float4*>(x)[i];
  uint2 o;
  o.x = (unsigned int)f2b(v.x * di) | ((unsigned int)f2b(v.y * di) << 16);
  o.y = (unsigned int)f2b(v.z * di) | ((unsigned int)f2b(v.w * di) << 16);
  reinterpret_cast<uint2*>(xh)[i] = o;
}

// --- bucket cursors: segmented regions of CAP slots, line-padded ---
__global__ void k_binit(int* __restrict__ gcur, int nc) {
  int b = blockIdx.x * 256 + threadIdx.x;
  if (b < nc) gcur[b * GPAD] = b * CAP;
}

// --- pass1: block-local counting sort by bucket, coalesced write-out ---
__global__ __launch_bounds__(256) void k_pass1(const int* __restrict__ src,
                                               const int* __restrict__ dst,
                                               int* __restrict__ gcur,
                                               int* __restrict__ P,
                                               int E, int nc, int seg) {
  __shared__ int hist[MAXC];
  __shared__ int lofs[MAXC];
  __shared__ int base[MAXC];
  __shared__ int sbuf[SEG];
  __shared__ unsigned short dbuf[SEG];
  __shared__ int ssc[256];
  int tid = threadIdx.x;
  int start = blockIdx.x * seg;
  int end = min(E, start + seg);
  int cnt = end - start;
  if (cnt <= 0) return;
  for (int i = tid; i < MAXC; i += 256) hist[i] = 0;
  __syncthreads();
  for (int i = start + tid; i < end; i += 256)
    atomicAdd(&hist[dst[i] >> 8], 1);
  __syncthreads();
  int p0 = hist[2 * tid], p1 = hist[2 * tid + 1];
  int ps = p0 + p1;
  ssc[tid] = ps;
  __syncthreads();
  for (int off = 1; off < 256; off <<= 1) {
    int t = (tid >= off) ? ssc[tid - off] : 0;
    __syncthreads();
    ssc[tid] += t;
    __syncthreads();
  }
  int pe = ssc[tid] - ps;
  lofs[2 * tid] = pe;
  lofs[2 * tid + 1] = pe + p0;
  __syncthreads();
  for (int b = tid; b < nc; b += 256) {
    int h = hist[b];
    base[b] = (h ? atomicAdd(&gcur[b * GPAD], h) : 0) - lofs[b];
  }
  __syncthreads();
  for (int i = tid; i < MAXC; i += 256) hist[i] = lofs[i];
  __syncthreads();
  for (int i = start + tid; i < end; i += 256) {
    int d = dst[i];
    int b = d >> 8;
    int r = atomicAdd(&hist[b], 1);
    sbuf[r] = src[i] | ((d & 255) << 17);
    dbuf[r] = (unsigned short)b;
  }
  __syncthreads();
  for (int j = tid; j < cnt; j += 256) {
    P[base[dbuf[j]] + j] = sbuf[j];
  }
}

// --- per-bucket: LDS count+scan -> rs/c/dinv, then place col ---
__global__ __launch_bounds__(256) void k_pass2(const int* __restrict__ P,
                                               const int* __restrict__ gcur,
                                               int* __restrict__ rs,
                                               int* __restrict__ c,
                                               float* __restrict__ dinv,
                                               int* __restrict__ col, int N) {
  __shared__ int sh[256];
  __shared__ int lcur[256];
  int tid = threadIdx.x;
  int node0 = blockIdx.x << 8;
  int begin = blockIdx.x * CAP;
  int end = gcur[blockIdx.x * GPAD];
  sh[tid] = 0;
  __syncthreads();
  for (int i = begin + tid; i < end; i += 256)
    atomicAdd(&sh[P[i] >> 17], 1);
  __syncthreads();
  int s = sh[tid];
  for (int off = 1; off < 256; off <<= 1) {
    int t = (tid >= off) ? sh[tid - off] : 0;
    __syncthreads();
    sh[tid] += t;
    __syncthreads();
  }
  int excl = sh[tid] - s;
  int node = node0 + tid;
  if (node < N) {
    rs[node] = begin + excl;
    c[node] = s;
    dinv[node] = rsqrtf((float)(s + 1));
  }
  lcur[tid] = begin + excl;
  __syncthreads();
  for (int i = begin + tid; i < end; i += 256) {
    int p = P[i];
    int pos = atomicAdd(&lcur[p >> 17], 1);
    col[pos] = p & 0x1FFFF;
  }
}

// --- pull1: 16-lane group per node, broadcast col, 8-deep gather unroll ---
__global__ __launch_bounds__(256) void k_pull1(const unsigned int* __restrict__ xh,
                                               const int* __restrict__ rs,
                                               const int* __restrict__ cnt,
                                               const int* __restrict__ col,
                                               const float* __restrict__ dinv,
                                               unsigned int* __restrict__ aggh,
                                               int n) {
  int tid = threadIdx.x;
  int q = tid & 15;
  int node = (blockIdx.x * 256 + tid) >> 4;  // 16 nodes per block
  bool valid = node < n;
  int nidx = valid ? node : 0;
  int start = rs[nidx];
  int m = valid ? cnt[nidx] : 0;
  const uint2* xr = reinterpret_cast<const uint2*>(xh);
  const int* cp = col + start;
  float4 acc = {0.f, 0.f, 0.f, 0.f};
  int t = 0;
  for (; t + 8 <= m; t += 8) {
    int i0 = cp[t],     i1 = cp[t + 1], i2 = cp[t + 2], i3 = cp[t + 3];
    int i4 = cp[t + 4], i5 = cp[t + 5], i6 = cp[t + 6], i7 = cp[t + 7];
    uint2 v0 = xr[i0 * 16 + q], v1 = xr[i1 * 16 + q];
    uint2 v2 = xr[i2 * 16 + q], v3 = xr[i3 * 16 + q];
    uint2 v4 = xr[i4 * 16 + q], v5 = xr[i5 * 16 + q];
    uint2 v6 = xr[i6 * 16 + q], v7 = xr[i7 * 16 + q];
    acc.x += ((blo(v0.x) + blo(v1.x)) + (blo(v2.x) + blo(v3.x)))
           + ((blo(v4.x) + blo(v5.x)) + (blo(v6.x) + blo(v7.x)));
    acc.y += ((bhi(v0.x) + bhi(v1.x)) + (bhi(v2.x) + bhi(v3.x)))
           + ((bhi(v4.x) + bhi(v5.x)) + (bhi(v6.x) + bhi(v7.x)));
    acc.z += ((blo(v0.y) + blo(v1.y)) + (blo(v2.y) + blo(v3.y)))
           + ((blo(v4.y) + blo(v5.y)) + (blo(v6.y) + blo(v7.y)));
    acc.w += ((bhi(v0.y) + bhi(v1.y)) + (bhi(v2.y) + bhi(v3.y)))
           + ((bhi(v4.y) + bhi(v5.y)) + (bhi(v6.y) + bhi(v7.y)));
  }
  for (; t + 4 <= m; t += 4) {
    int i0 = cp[t], i1 = cp[t + 1], i2 = cp[t + 2], i3 = cp[t + 3];
    uint2 v0 = xr[i0 * 16 + q], v1 = xr[i1 * 16 + q];
    uint2 v2 = xr[i2 * 16 + q], v3 = xr[i3 * 16 + q];
    acc.x += (blo(v0.x) + blo(v1.x)) + (blo(v2.x) + blo(v3.x));
    acc.y += (bhi(v0.x) + bhi(v1.x)) + (bhi(v2.x) + bhi(v3.x));
    acc.z += (blo(v0.y) + blo(v1.y)) + (blo(v2.y) + blo(v3.y));
    acc.w += (bhi(v0.y) + bhi(v1.y)) + (bhi(v2.y) + bhi(v3.y));
  }
  for (; t < m; ++t) {
    int i0 = cp[t];
    uint2 v0 = xr[i0 * 16 + q];
    acc.x += blo(v0.x); acc.y += bhi(v0.x);
    acc.z += blo(v0.y); acc.w += bhi(v0.y);
  }
  if (valid) {
    uint2 sv = xr[node * 16 + q];  // self term: xh already = bf16(di*x)
    acc.x += blo(sv.x); acc.y += bhi(sv.x);
    acc.z += blo(sv.y); acc.w += bhi(sv.y);
    float di = dinv[node];
    uint2 o;
    o.x = (unsigned int)f2b(acc.x * di) | ((unsigned int)f2b(acc.y * di) << 16);
    o.y = (unsigned int)f2b(acc.z * di) | ((unsigned int)f2b(acc.w * di) << 16);
    reinterpret_cast<uint2*>(aggh)[node * 16 + q] = o;
  }
}

// --- fused gemm12: g2h = bf16(dinv ⊙ relu(aggh@W1+b1)@W2), bf16 MFMA ---
// LDS (80KB, 2 blocks/CU): aggh[128][64]bf16 @0, W1t[128][64]bf16 @16K,
// W2t[64][128]bf16 @32K, h1[128][128]bf16 / C2[128][64]f32 (reused) @48K.
// All tiles XOR-swizzled (T2).
#define OFF_W1T 16384
#define OFF_W2T 32768
#define OFF_H1  49152
__global__ __launch_bounds__(256) void k_gemm12(
    const unsigned int* __restrict__ aggh,
    const float* __restrict__ W1, const float* __restrict__ b1,
    const float* __restrict__ W2, const float* __restrict__ dinv,
    unsigned int* __restrict__ g2h, int n) {
  __shared__ __align__(16) char smem[81920];
  int tid = threadIdx.x;
  int lane = tid & 63;
  int wid = tid >> 6;
  int lr = lane & 15, lg = lane >> 4;
  int wr = wid >> 1, wc = wid & 1;
  // stage W1t bf16 [ncol=128][k=64]
  {
    int nrow = tid >> 1, h = tid & 1;
    unsigned int pk[16];
#pragma unroll
    for (int q = 0; q < 16; ++q) {
      unsigned short a = f2b(W1[(size_t)(h * 32 + 2 * q) * 128 + nrow]);
      unsigned short bq = f2b(W1[(size_t)(h * 32 + 2 * q + 1) * 128 + nrow]);
      pk[q] = (unsigned int)a | ((unsigned int)bq << 16);
    }
#pragma unroll
    for (int cc = 0; cc < 4; ++cc) {
      uint4 v = make_uint4(pk[cc * 4], pk[cc * 4 + 1], pk[cc * 4 + 2], pk[cc * 4 + 3]);
      int byte = nrow * 128 + ((h * 64 + cc * 16) ^ ((nrow & 7) << 4));
      *reinterpret_cast<uint4*>(smem + OFF_W1T + byte) = v;
    }
  }
  // stage W2t bf16 [ncol=64][k=128]
  {
    int nrow = tid >> 2, qt = tid & 3;
    unsigned int pk[16];
#pragma unroll
    for (int q = 0; q < 16; ++q) {
      unsigned short a = f2b(W2[(size_t)(qt * 32 + 2 * q) * 64 + nrow]);
      unsigned short bq = f2b(W2[(size_t)(qt * 32 + 2 * q + 1) * 64 + nrow]);
      pk[q] = (unsigned int)a | ((unsigned int)bq << 16);
    }
#pragma unroll
    for (int cc = 0; cc < 4; ++cc) {
      uint4 v = make_uint4(pk[cc * 4], pk[cc * 4 + 1], pk[cc * 4 + 2], pk[cc * 4 + 3]);
      int byte = nrow * 256 + ((qt * 64 + cc * 16) ^ ((nrow & 7) << 4));
      *reinterpret_cast<uint4*>(smem + OFF_W2T + byte) = v;
    }
  }
  float bias[4];
#pragma unroll
  for (int ni = 0; ni < 4; ++ni) bias[ni] = b1[wc * 64 + ni * 16 + lr];

  int ntiles = (n + 127) >> 7;
  for (int tile = blockIdx.x; tile < ntiles; tile += gridDim.x) {
    int row0 = tile << 7;
    __syncthreads();
#pragma unroll
    for (int j = 0; j < 4; ++j) {
      int idx = tid + 256 * j;
      int r = idx >> 3, u = idx & 7;
      uint4 v = make_uint4(0u, 0u, 0u, 0u);
      int row = row0 + r;
      if (row < n) v = reinterpret_cast<const uint4*>(aggh)[(size_t)row * 8 + u];
      int byte = r * 128 + ((u * 16) ^ ((r & 7) << 4));
      *reinterpret_cast<uint4*>(smem + byte) = v;
    }
    __syncthreads();
    f32x4 acc1[4][4];
#pragma unroll
    for (int mi = 0; mi < 4; ++mi)
#pragma unroll
      for (int ni = 0; ni < 4; ++ni) {
        f32x4 z = {0.f, 0.f, 0.f, 0.f};
        acc1[mi][ni] = z;
      }
#pragma unroll
    for (int kk = 0; kk < 2; ++kk) {
      int kb = kk * 64 + lg * 16;
      bf16x8 af[4], bfq[4];
#pragma unroll
      for (int mi = 0; mi < 4; ++mi) {
        int r = wr * 64 + mi * 16 + lr;
        af[mi] = *reinterpret_cast<const bf16x8*>(smem + r * 128 + (kb ^ ((r & 7) << 4)));
      }
#pragma unroll
      for (int ni = 0; ni < 4; ++ni) {
        int nr = wc * 64 + ni * 16 + lr;
        bfq[ni] = *reinterpret_cast<const bf16x8*>(smem + OFF_W1T + nr * 128 + (kb ^ ((nr & 7) << 4)));
      }
#pragma unroll
      for (int mi = 0; mi < 4; ++mi)
#pragma unroll
        for (int ni = 0; ni < 4; ++ni)
          acc1[mi][ni] = __builtin_amdgcn_mfma_f32_16x16x32_bf16(
              af[mi], bfq[ni], acc1[mi][ni], 0, 0, 0);
    }
#pragma unroll
    for (int mi = 0; mi < 4; ++mi) {
      int m0 = wr * 64 + mi * 16 + lg * 4;
#pragma unroll
      for (int ni = 0; ni < 4; ++ni) {
        int kcol = wc * 64 + ni * 16 + lr;
#pragma unroll
        for (int rj = 0; rj < 4; ++rj) {
          float v = fmaxf(acc1[mi][ni][rj] + bias[ni], 0.f);
          int mm = m0 + rj;
          int byte = mm * 256 + ((kcol * 2) ^ ((mm & 15) << 4));
          *reinterpret_cast<unsigned short*>(smem + OFF_H1 + byte) = f2b(v);
        }
      }
    }
    __syncthreads();
    f32x4 acc2[4][2];
#pragma unroll
    for (int mi = 0; mi < 4; ++mi)
#pragma unroll
      for (int ni = 0; ni < 2; ++ni) {
        f32x4 z = {0.f, 0.f, 0.f, 0.f};
        acc2[mi][ni] = z;
      }
#pragma unroll
    for (int kk = 0; kk < 4; ++kk) {
      int kb = kk * 64 + lg * 16;
      bf16x8 af[4], bfq[2];
#pragma unroll
      for (int mi = 0; mi < 4; ++mi) {
        int m = wr * 64 + mi * 16 + lr;
        af[mi] = *reinterpret_cast<const bf16x8*>(smem + OFF_H1 + m * 256 + (kb ^ ((m & 15) << 4)));
      }
#pragma unroll
      for (int ni = 0; ni < 2; ++ni) {
        int nr = wc * 32 + ni * 16 + lr;
        bfq[ni] = *reinterpret_cast<const bf16x8*>(smem + OFF_W2T + nr * 256 + (kb ^ ((nr & 7) << 4)));
      }
#pragma unroll
      for (int mi = 0; mi < 4; ++mi)
#pragma unroll
        for (int ni = 0; ni < 2; ++ni)
          acc2[mi][ni] = __builtin_amdgcn_mfma_f32_16x16x32_bf16(
              af[mi], bfq[ni], acc2[mi][ni], 0, 0, 0);
    }
    __syncthreads();
#pragma unroll
    for (int mi = 0; mi < 4; ++mi) {
      int m0 = wr * 64 + mi * 16 + lg * 4;
#pragma unroll
      for (int ni = 0; ni < 2; ++ni) {
        int nn = wc * 32 + ni * 16 + lr;
#pragma unroll
        for (int rj = 0; rj < 4; ++rj) {
          int mm = m0 + rj;
          int byte = mm * 256 + ((nn * 4) ^ ((mm & 15) << 4));
          *reinterpret_cast<float*>(smem + OFF_H1 + byte) = acc2[mi][ni][rj];
        }
      }
    }
    __syncthreads();
#pragma unroll
    for (int j = 0; j < 8; ++j) {
      int idx = tid + 256 * j;
      int r = idx >> 4, c4 = idx & 15;
      int row = row0 + r;
      if (row < n) {
        float4 v = *reinterpret_cast<const float4*>(
            smem + OFF_H1 + r * 256 + ((c4 * 16) ^ ((r & 15) << 4)));
        float di = dinv[row];
        uint2 o;
        o.x = (unsigned int)f2b(v.x * di) | ((unsigned int)f2b(v.y * di) << 16);
        o.y = (unsigned int)f2b(v.z * di) | ((unsigned int)f2b(v.w * di) << 16);
        reinterpret_cast<uint2*>(g2h)[(size_t)row * 16 + c4] = o;
      }
    }
  }
}

// --- pull2: 16-lane group per node, bcast col, relu + both heads fused ---
__global__ __launch_bounds__(256) void k_pull2(const unsigned int* __restrict__ g2h,
                                               const int* __restrict__ rs,
                                               const int* __restrict__ cnt,
                                               const int* __restrict__ col,
                                               const float* __restrict__ dinv,
                                               const float* __restrict__ b,
                                               const float* __restrict__ Wd,
                                               const float* __restrict__ Wp,
                                               const float* __restrict__ bd,
                                               const float* __restrict__ bp,
                                               float* __restrict__ out, int n) {
  int tid = threadIdx.x;
  int q = tid & 15;
  int node = (blockIdx.x * 256 + tid) >> 4;
  bool valid = node < n;
  int nidx = valid ? node : 0;
  int start = rs[nidx];
  int m = valid ? cnt[nidx] : 0;
  const uint2* gr = reinterpret_cast<const uint2*>(g2h);
  const int* cp = col + start;
  float4 acc = {0.f, 0.f, 0.f, 0.f};
  int t = 0;
  for (; t + 8 <= m; t += 8) {
    int i0 = cp[t],     i1 = cp[t + 1], i2 = cp[t + 2], i3 = cp[t + 3];
    int i4 = cp[t + 4], i5 = cp[t + 5], i6 = cp[t + 6], i7 = cp[t + 7];
    uint2 v0 = gr[i0 * 16 + q], v1 = gr[i1 * 16 + q];
    uint2 v2 = gr[i2 * 16 + q], v3 = gr[i3 * 16 + q];
    uint2 v4 = gr[i4 * 16 + q], v5 = gr[i5 * 16 + q];
    uint2 v6 = gr[i6 * 16 + q], v7 = gr[i7 * 16 + q];
    acc.x += ((blo(v0.x) + blo(v1.x)) + (blo(v2.x) + blo(v3.x)))
           + ((blo(v4.x) + blo(v5.x)) + (blo(v6.x) + blo(v7.x)));
    acc.y += ((bhi(v0.x) + bhi(v1.x)) + (bhi(v2.x) + bhi(v3.x)))
           + ((bhi(v4.x) + bhi(v5.x)) + (bhi(v6.x) + bhi(v7.x)));
    acc.z += ((blo(v0.y) + blo(v1.y)) + (blo(v2.y) + blo(v3.y)))
           + ((blo(v4.y) + blo(v5.y)) + (blo(v6.y) + blo(v7.y)));
    acc.w += ((bhi(v0.y) + bhi(v1.y)) + (bhi(v2.y) + bhi(v3.y)))
           + ((bhi(v4.y) + bhi(v5.y)) + (bhi(v6.y) + bhi(v7.y)));
  }
  for (; t + 4 <= m; t += 4) {
    int i0 = cp[t], i1 = cp[t + 1], i2 = cp[t + 2], i3 = cp[t + 3];
    uint2 v0 = gr[i0 * 16 + q], v1 = gr[i1 * 16 + q];
    uint2 v2 = gr[i2 * 16 + q], v3 = gr[i3 * 16 + q];
    acc.x += (blo(v0.x) + blo(v1.x)) + (blo(v2.x) + blo(v3.x));
    acc.y += (bhi(v0.x) + bhi(v1.x)) + (bhi(v2.x) + bhi(v3.x));
    acc.z += (blo(v0.y) + blo(v1.y)) + (blo(v2.y) + blo(v3.y));
    acc.w += (bhi(v0.y) + bhi(v1.y)) + (bhi(v2.y) + bhi(v3.y));
  }
  for (; t < m; ++t) {
    int i0 = cp[t];
    uint2 v0 = gr[i0 * 16 + q];
    acc.x += blo(v0.x); acc.y += bhi(v0.x);
    acc.z += blo(v0.y); acc.w += bhi(v0.y);
  }
  {
    uint2 sv = gr[nidx * 16 + q];  // self term
    acc.x += blo(sv.x); acc.y += bhi(sv.x);
    acc.z += blo(sv.y); acc.w += bhi(sv.y);
  }
  float di = dinv[nidx];
  float4 b4 = *reinterpret_cast<const float4*>(b + q * 4);
  float4 wd4 = *reinterpret_cast<const float4*>(Wd + q * 4);
  float4 wp4 = *reinterpret_cast<const float4*>(Wp + q * 4);
  float vx = fmaxf(fmaf(acc.x, di, b4.x), 0.f);
  float vy = fmaxf(fmaf(acc.y, di, b4.y), 0.f);
  float vz = fmaxf(fmaf(acc.z, di, b4.z), 0.f);
  float vw = fmaxf(fmaf(acc.w, di, b4.w), 0.f);
  float dsum = vx * wd4.x + vy * wd4.y + vz * wd4.z + vw * wd4.w;
  float psum = vx * wp4.x + vy * wp4.y + vz * wp4.z + vw * wp4.w;
#pragma unroll
  for (int off = 1; off < 16; off <<= 1) {
    dsum += __shfl_xor(dsum, off);
    psum += __shfl_xor(psum, off);
  }
  if (valid && q == 0) {
    out[node] = dsum + bd[0];
    out[n + node] = psum + bp[0];
  }
}

extern "C" void kernel_launch(void* const* d_in, const int* in_sizes, int n_in,
                              void* d_out, int out_size, void* d_ws, size_t ws_size,
                              hipStream_t stream) {
  const float* x  = (const float*)d_in[0];
  const int*   ei = (const int*)d_in[1];
  const float* W1 = (const float*)d_in[2];
  const float* b1 = (const float*)d_in[3];
  const float* W2 = (const float*)d_in[4];
  const float* b2 = (const float*)d_in[5];
  const float* Wd = (const float*)d_in[6];
  const float* bd = (const float*)d_in[7];
  const float* Wp = (const float*)d_in[8];
  const float* bp = (const float*)d_in[9];
  float* out = (float*)d_out;

  const int N = in_sizes[0] / 64;
  const int E = in_sizes[1] / 2;
  const int* src = ei;
  const int* dst = ei + E;
  const int nc = (N + 255) >> 8;

  char* ws = (char*)d_ws;
  size_t off = 0;
  auto alloc = [&](size_t bytes) -> void* {
    size_t a = (off + 255) & ~(size_t)255;
    off = a + bytes;
    return (void*)(ws + a);
  };

  int*   gcur = (int*)alloc((size_t)MAXC * GPAD * 4);
  int*   rs   = (int*)alloc((size_t)N * 4);
  int*   c    = (int*)alloc((size_t)N * 4);
  float* dinv = (float*)alloc((size_t)N * 4);
  int*   P    = (int*)alloc((size_t)nc * CAP * 4);
  int*   col  = (int*)alloc((size_t)nc * CAP * 4);
  unsigned int* xh   = (unsigned int*)alloc((size_t)N * 64 * 2);
  unsigned int* aggh = (unsigned int*)alloc((size_t)N * 64 * 2);
  unsigned int* g2h  = (unsigned int*)alloc((size_t)N * 64 * 2);
  (void)ws_size; (void)n_in; (void)out_size;

  k_binit<<<(nc + 255) / 256, 256, 0, stream>>>(gcur, nc);

  int nb1 = 512;
  int seg = (E + nb1 - 1) / nb1;
  while (seg > SEG) { nb1 *= 2; seg = (E + nb1 - 1) / nb1; }
  k_pass1<<<nb1, 256, 0, stream>>>(src, dst, gcur, P, E, nc, seg);
  k_pass2<<<nc, 256, 0, stream>>>(P, gcur, rs, c, dinv, col, N);

  k_cast<<<(N * 16 + 255) / 256, 256, 0, stream>>>(x, dinv, xh, N * 16);
  k_pull1<<<(N + 15) / 16, 256, 0, stream>>>(xh, rs, c, col, dinv, aggh, N);
  k_gemm12<<<512, 256, 0, stream>>>(aggh, W1, b1, W2, dinv, g2h, N);
  k_pull2<<<(N + 15) / 16, 256, 0, stream>>>(g2h, rs, c, col, dinv, b2, Wd, Wp, bd, bp, out, N);
}